// Round 6
// baseline (2488.622 us; speedup 1.0000x reference)
//
#include <hip/hip_runtime.h>
#include <hip/hip_bf16.h>
#include <math.h>

#define E_DIM 1024
#define NHEAD 16
#define HID_DIM 2730
#define KP_FC2 2816            // fc2 K padded so nk=88 (mult of 4)
#define B_DIM 8
#define S_DIM 1025
#define EPS_V 1e-6f
#define SCALE_V 0.125f
#define MROWS (B_DIM * S_DIM)   // 8200

typedef __attribute__((ext_vector_type(8))) short short8;
typedef __attribute__((ext_vector_type(4))) float f32x4;

__device__ __forceinline__ float b2f(unsigned short u) {
    union { unsigned int i; float f; } x; x.i = ((unsigned int)u) << 16; return x.f;
}
__device__ __forceinline__ unsigned short f2b(float f) {
    __hip_bfloat16 h = __float2bfloat16(f);
    return *reinterpret_cast<unsigned short*>(&h);
}

__device__ __forceinline__ void stage16(const void* g, void* l) {
    __builtin_amdgcn_global_load_lds(
        (const __attribute__((address_space(1))) unsigned int*)g,
        (__attribute__((address_space(3))) unsigned int*)l,
        16, 0, 0);
}

// raw barrier: waits LDS ops only (lgkmcnt(0)); leaves global loads in flight.
// imm 0xC07F = vmcnt 63 (no wait), expcnt 7 (no wait), lgkmcnt 0.
__device__ __forceinline__ void barrier_lds() {
    __asm__ __volatile__("" ::: "memory");
    __builtin_amdgcn_s_waitcnt(0xC07F);
    __builtin_amdgcn_s_barrier();
    __asm__ __volatile__("" ::: "memory");
}

// u16 index of the 8-element group at (row, c8) in a XOR-swizzled [64][64] bf16 tile
__device__ __forceinline__ int sl(int row, int c8) {
    return (row * 8 + (c8 ^ (row & 7))) * 8;
}

// ---------------- RMSNorm (fp32 in -> bf16 out) ----------------
__global__ __launch_bounds__(256) void rmsnorm_kernel(const float* __restrict__ x,
        const float* __restrict__ g, unsigned short* __restrict__ out) {
    int row = blockIdx.x;
    const float4* xr = (const float4*)(x + (size_t)row * E_DIM);
    float4 v = xr[threadIdx.x];
    float ss = v.x*v.x + v.y*v.y + v.z*v.z + v.w*v.w;
    #pragma unroll
    for (int off = 32; off > 0; off >>= 1) ss += __shfl_down(ss, off, 64);
    __shared__ float wsum[4];
    int lane = threadIdx.x & 63, w = threadIdx.x >> 6;
    if (lane == 0) wsum[w] = ss;
    __syncthreads();
    float tot = wsum[0] + wsum[1] + wsum[2] + wsum[3];
    float inv = rsqrtf(tot * (1.0f / E_DIM) + EPS_V);
    float4 gv = ((const float4*)g)[threadIdx.x];
    ushort4 o;
    o.x = f2b(v.x * inv * gv.x); o.y = f2b(v.y * inv * gv.y);
    o.z = f2b(v.z * inv * gv.z); o.w = f2b(v.w * inv * gv.w);
    ((ushort4*)(out + (size_t)row * E_DIM))[threadIdx.x] = o;
}

// ---------------- weight convert+transpose: W[K][N] f32 -> WT[n][k] bf16 ----------------
__global__ __launch_bounds__(256) void convt_kernel(const float* __restrict__ W,
        unsigned short* __restrict__ WT, int K, int N, int KPad) {
    __shared__ float T[32][33];
    int n0 = blockIdx.x * 32, k0 = blockIdx.y * 32;
    int c = threadIdx.x & 31, r4 = (threadIdx.x >> 5) << 2;
    #pragma unroll
    for (int i = 0; i < 4; i++) {
        int k = k0 + r4 + i, n = n0 + c;
        T[c][r4 + i] = (k < K && n < N) ? W[(size_t)k * N + n] : 0.0f;
    }
    __syncthreads();
    #pragma unroll
    for (int i = 0; i < 4; i++) {
        int n = n0 + r4 + i, k = k0 + c;
        if (n < N && k < KPad) WT[(size_t)n * KPad + k] = f2b(T[r4 + i][c]);
    }
}

// ---------------- bf16 MFMA GEMM with depth-4 VGPR ring pipeline ----------------
// A: [M][K] bf16, Bt: [N][K] bf16, K % 128 == 0 (nk mult of 4, nk >= 4).
// Loads stay in flight across raw barriers; compiler emits fine-grained vmcnt
// only at each ds_write (AITER-style, never vmcnt(0)).
template<bool BF16OUT>
__global__ __launch_bounds__(256) void gemm_ring(const unsigned short* __restrict__ A,
        const unsigned short* __restrict__ Bt, const float* __restrict__ bias,
        const float* __restrict__ R, void* __restrict__ Cv,
        int M, int N, int K, int ldc) {
    __shared__ __align__(16) unsigned short ldsA[4096];   // [kc 0..3][row 0..127] x 8 bf16
    __shared__ __align__(16) unsigned short ldsB[4096];
    int tid = threadIdx.x;
    int lane = tid & 63;
    int w = tid >> 6;
    int wm = w >> 1, wn = w & 1;
    int m0 = blockIdx.y * 128, n0 = blockIdx.x * 128;

    int c0 = 2 * w, c1 = 2 * w + 1;
    int kc0 = c0 & 3, rh0 = (c0 >> 2) * 64;
    int kc1 = c1 & 3, rh1 = (c1 >> 2) * 64;
    const uint4* gA0 = (const uint4*)(A + (size_t)(m0 + rh0 + lane) * K + kc0 * 8);
    const uint4* gA1 = (const uint4*)(A + (size_t)(m0 + rh1 + lane) * K + kc1 * 8);
    const uint4* gB0 = (const uint4*)(Bt + (size_t)(n0 + rh0 + lane) * K + kc0 * 8);
    const uint4* gB1 = (const uint4*)(Bt + (size_t)(n0 + rh1 + lane) * K + kc1 * 8);
    // per-lane LDS write pointers (same layout stage16 produced)
    uint4* wA0 = (uint4*)&ldsA[(kc0 * 128 + rh0 + lane) * 8];
    uint4* wA1 = (uint4*)&ldsA[(kc1 * 128 + rh1 + lane) * 8];
    uint4* wB0 = (uint4*)&ldsB[(kc0 * 128 + rh0 + lane) * 8];
    uint4* wB1 = (uint4*)&ldsB[(kc1 * 128 + rh1 + lane) * 8];

    f32x4 acc[4][4];
    #pragma unroll
    for (int i = 0; i < 4; i++)
        #pragma unroll
        for (int j = 0; j < 4; j++) acc[i][j] = (f32x4){0.f, 0.f, 0.f, 0.f};

    const unsigned short* pa = ldsA + ((lane >> 4) * 128 + wm * 64 + (lane & 15)) * 8;
    const unsigned short* pb = ldsB + ((lane >> 4) * 128 + wn * 64 + (lane & 15)) * 8;

    int nk = K >> 5;                 // multiple of 4, >= 4
    uint4 rA0[4], rA1[4], rB0[4], rB1[4];
    #pragma unroll
    for (int d = 0; d < 4; d++) {    // prologue: tiles 0..3 in flight
        rA0[d] = gA0[4 * d]; rA1[d] = gA1[4 * d];
        rB0[d] = gB0[4 * d]; rB1[d] = gB1[4 * d];
    }

    for (int t = 0; t < nk; t += 4) {
        #pragma unroll
        for (int u = 0; u < 4; u++) {
            // commit tile t+u to LDS (compiler waits vmcnt(N) for just these regs)
            *wA0 = rA0[u]; *wA1 = rA1[u];
            *wB0 = rB0[u]; *wB1 = rB1[u];
            barrier_lds();
            int tn = t + u + 4;      // uniform guard — no divergent barrier
            if (tn < nk) {
                rA0[u] = gA0[4 * tn]; rA1[u] = gA1[4 * tn];
                rB0[u] = gB0[4 * tn]; rB1[u] = gB1[4 * tn];
            }
            short8 af[4], bfr[4];
            #pragma unroll
            for (int i = 0; i < 4; i++) af[i] = *(const short8*)(pa + i * 128);
            #pragma unroll
            for (int j = 0; j < 4; j++) bfr[j] = *(const short8*)(pb + j * 128);
            #pragma unroll
            for (int i = 0; i < 4; i++)
                #pragma unroll
                for (int j = 0; j < 4; j++)
                    acc[i][j] = __builtin_amdgcn_mfma_f32_16x16x32_bf16(af[i], bfr[j], acc[i][j], 0, 0, 0);
            barrier_lds();           // all reads done before next ds_write
        }
    }

    int cr = (lane >> 4) * 4;
    int cc = lane & 15;
    #pragma unroll
    for (int i = 0; i < 4; i++) {
        int gmb = m0 + wm * 64 + i * 16 + cr;
        #pragma unroll
        for (int j = 0; j < 4; j++) {
            int gn = n0 + wn * 64 + j * 16 + cc;
            if (gn >= N) continue;
            float bs = bias[gn];
            #pragma unroll
            for (int r = 0; r < 4; r++) {
                int gm = gmb + r;
                if (gm >= M) continue;
                float v = acc[i][j][r] + bs;
                if (BF16OUT) {
                    ((unsigned short*)Cv)[(size_t)gm * ldc + gn] = f2b(v);
                } else {
                    ((float*)Cv)[(size_t)gm * ldc + gn] = v + R[(size_t)gm * ldc + gn];
                }
            }
        }
    }
}

// ---------------- RoPE (per 2-batch chunk, in-place, rows 0..2049) ----------------
__global__ __launch_bounds__(256) void rope_kernel(unsigned short* __restrict__ qkv2) {
    int idx = blockIdx.x * 256 + threadIdx.x;
    int i = idx & 31;
    int h = (idx >> 5) & (NHEAD - 1);
    int rc = idx >> 9;
    int s = (rc < S_DIM) ? rc : rc - S_DIM;
    unsigned short* q = qkv2 + (size_t)rc * 3072 + h * 64;
    unsigned short* k = q + 1024;
    if (s == 0) {
        q[i] = f2b(b2f(q[i]) * SCALE_V);
        q[i + 32] = f2b(b2f(q[i + 32]) * SCALE_V);
        return;
    }
    float pos = (float)(s - 1);
    float invf = expf((float)i * (-9.210340371976184f / 32.0f));
    float f = pos * invf;
    float c = cosf(f), sn = sinf(f);
    float q1 = b2f(q[i]), q2 = b2f(q[i + 32]);
    q[i]      = f2b((q1 * c - q2 * sn) * SCALE_V);
    q[i + 32] = f2b((q2 * c + q1 * sn) * SCALE_V);
    float k1 = b2f(k[i]), k2 = b2f(k[i + 32]);
    k[i]      = f2b(k1 * c - k2 * sn);
    k[i + 32] = f2b(k2 * c + k1 * sn);
}

// ---------------- V transpose: qkv2 v-section -> Vt[bc][h][d][1088] ----------------
__global__ __launch_bounds__(256) void vtrans_kernel(const unsigned short* __restrict__ qkv2,
        unsigned short* __restrict__ Vt) {
    __shared__ unsigned short T[64][65];
    int st = blockIdx.x, h = blockIdx.y, bc = blockIdx.z;
    int tid = threadIdx.x;
    int r = tid & 63, cb = (tid >> 6) * 16;
    const unsigned short* src = qkv2 + (size_t)(bc * S_DIM + st * 64 + r) * 3072 + 2048 + h * 64 + cb;
    #pragma unroll
    for (int i = 0; i < 4; i++) {
        ushort4 v = *(const ushort4*)(src + i * 4);
        T[cb + i*4 + 0][r] = v.x; T[cb + i*4 + 1][r] = v.y;
        T[cb + i*4 + 2][r] = v.z; T[cb + i*4 + 3][r] = v.w;
    }
    __syncthreads();
    int d = tid >> 2, sc = (tid & 3) * 16;
    unsigned short* dst = Vt + ((size_t)((bc * 16 + h) * 64 + d)) * 1088 + st * 64 + sc;
    #pragma unroll
    for (int g = 0; g < 4; g++) {
        ushort4 o;
        int i0 = sc + g * 4;
        o.x = (st*64 + i0 + 0 < S_DIM) ? T[d][i0 + 0] : 0;
        o.y = (st*64 + i0 + 1 < S_DIM) ? T[d][i0 + 1] : 0;
        o.z = (st*64 + i0 + 2 < S_DIM) ? T[d][i0 + 2] : 0;
        o.w = (st*64 + i0 + 3 < S_DIM) ? T[d][i0 + 3] : 0;
        *(ushort4*)(dst + g * 4) = o;
    }
}

// ---------------- MFMA flash attention (per 2-batch chunk) ----------------
__global__ __launch_bounds__(256) void attn_kernel(const unsigned short* __restrict__ qkv2,
        const unsigned short* __restrict__ Vt, unsigned short* __restrict__ attnb) {
    __shared__ __align__(16) unsigned short Qs[4096];
    __shared__ __align__(16) unsigned short Ks[4096];
    __shared__ __align__(16) unsigned short Vts[4096];
    __shared__ __align__(16) unsigned short Ps[4096];
    int qt = blockIdx.x, h = blockIdx.y, bc = blockIdx.z;
    int tid = threadIdx.x;
    int lane = tid & 63, w = tid >> 6;
    int l15 = lane & 15, quad = lane >> 4;

    const unsigned short* qg = qkv2 + (size_t)(bc * S_DIM + qt * 64) * 3072 + h * 64;
    #pragma unroll
    for (int i = 0; i < 2; i++) {
        int slot = i * 256 + tid;
        int row = slot >> 3, c8 = (slot & 7) ^ (row & 7);
        stage16(qg + (size_t)row * 3072 + c8 * 8, Qs + slot * 8);
    }
    const unsigned short* kg = qkv2 + (size_t)(bc * S_DIM) * 3072 + 1024 + h * 64;
    const unsigned short* vgp = Vt + (size_t)((bc * 16 + h) * 64) * 1088;

    f32x4 acc_o[4];
    float mr[4], lr[4];
    #pragma unroll
    for (int r = 0; r < 4; r++) { mr[r] = -1e30f; lr[r] = 0.f; }
    #pragma unroll
    for (int j = 0; j < 4; j++) acc_o[j] = (f32x4){0.f, 0.f, 0.f, 0.f};

    for (int kt = 0; kt < 17; kt++) {
        __syncthreads();
        #pragma unroll
        for (int i = 0; i < 2; i++) {
            int slot = i * 256 + tid;
            int row = slot >> 3, c8 = (slot & 7) ^ (row & 7);
            stage16(kg + (size_t)(kt * 64 + row) * 3072 + c8 * 8, Ks + slot * 8);
            stage16(vgp + (size_t)row * 1088 + kt * 64 + c8 * 8, Vts + slot * 8);
        }
        __syncthreads();

        f32x4 accS[4];
        #pragma unroll
        for (int j = 0; j < 4; j++) accS[j] = (f32x4){0.f, 0.f, 0.f, 0.f};
        short8 qa0 = *(const short8*)(Qs + sl(16 * w + l15, quad));
        short8 qa1 = *(const short8*)(Qs + sl(16 * w + l15, 4 + quad));
        #pragma unroll
        for (int j = 0; j < 4; j++) {
            short8 kb0 = *(const short8*)(Ks + sl(16 * j + l15, quad));
            short8 kb1 = *(const short8*)(Ks + sl(16 * j + l15, 4 + quad));
            accS[j] = __builtin_amdgcn_mfma_f32_16x16x32_bf16(qa0, kb0, accS[j], 0, 0, 0);
            accS[j] = __builtin_amdgcn_mfma_f32_16x16x32_bf16(qa1, kb1, accS[j], 0, 0, 0);
        }
        float pr[4][4];
        #pragma unroll
        for (int j = 0; j < 4; j++) {
            if (kt * 64 + 16 * j + l15 >= S_DIM) {
                #pragma unroll
                for (int r = 0; r < 4; r++) accS[j][r] = -1e30f;
            }
        }
        #pragma unroll
        for (int r = 0; r < 4; r++) {
            float tm = fmaxf(fmaxf(accS[0][r], accS[1][r]), fmaxf(accS[2][r], accS[3][r]));
            #pragma unroll
            for (int off = 1; off < 16; off <<= 1)
                tm = fmaxf(tm, __shfl_xor(tm, off, 64));
            float mnew = fmaxf(mr[r], tm);
            float al = __expf(mr[r] - mnew);
            mr[r] = mnew;
            float rs = 0.f;
            #pragma unroll
            for (int j = 0; j < 4; j++) {
                float p = __expf(accS[j][r] - mnew);
                pr[j][r] = p;
                rs += p;
            }
            #pragma unroll
            for (int off = 1; off < 16; off <<= 1)
                rs += __shfl_xor(rs, off, 64);
            lr[r] = lr[r] * al + rs;
            #pragma unroll
            for (int j = 0; j < 4; j++) acc_o[j][r] *= al;
        }
        #pragma unroll
        for (int j = 0; j < 4; j++) {
            #pragma unroll
            for (int r = 0; r < 4; r++) {
                int prow = quad * 4 + r;
                int idx = sl(16 * w + prow, 2 * j + (l15 >> 3)) + (l15 & 7);
                Ps[idx] = f2b(pr[j][r]);
            }
        }
        short8 pa0 = *(const short8*)(Ps + sl(16 * w + l15, quad));
        short8 pa1 = *(const short8*)(Ps + sl(16 * w + l15, 4 + quad));
        #pragma unroll
        for (int j = 0; j < 4; j++) {
            short8 vb0 = *(const short8*)(Vts + sl(16 * j + l15, quad));
            short8 vb1 = *(const short8*)(Vts + sl(16 * j + l15, 4 + quad));
            acc_o[j] = __builtin_amdgcn_mfma_f32_16x16x32_bf16(pa0, vb0, acc_o[j], 0, 0, 0);
            acc_o[j] = __builtin_amdgcn_mfma_f32_16x16x32_bf16(pa1, vb1, acc_o[j], 0, 0, 0);
        }
    }
    #pragma unroll
    for (int r = 0; r < 4; r++) {
        int s = qt * 64 + 16 * w + quad * 4 + r;
        if (s >= S_DIM) continue;
        float invl = 1.0f / lr[r];
        #pragma unroll
        for (int j = 0; j < 4; j++)
            attnb[(size_t)(bc * S_DIM + s) * E_DIM + h * 64 + 16 * j + l15] =
                f2b(acc_o[j][r] * invl);
    }
}

// ---------------- depthwise 3x3 conv + exact GELU + gate (2-batch chunk) ----------------
__global__ __launch_bounds__(256) void conv_gelu_kernel(const unsigned short* __restrict__ hb,
        const float* __restrict__ dw_w, const float* __restrict__ dw_b,
        unsigned short* __restrict__ act) {
    int p = blockIdx.x % S_DIM;
    size_t row = blockIdx.x;
    size_t brow = row - p;
    for (int c = threadIdx.x; c < KP_FC2; c += 256) {
        if (c >= HID_DIM) { act[row * KP_FC2 + c] = 0; continue; }
        float val;
        if (p == 0) {
            val = b2f(hb[row * 5460 + c]);
        } else {
            int pp = p - 1;
            int gy = pp >> 5, gx = pp & 31;
            float a = dw_b[c];
            #pragma unroll
            for (int dy = 0; dy < 3; dy++) {
                int ny = gy + dy - 1;
                if (ny < 0 || ny >= 32) continue;
                #pragma unroll
                for (int dx = 0; dx < 3; dx++) {
                    int nx = gx + dx - 1;
                    if (nx < 0 || nx >= 32) continue;
                    a = fmaf(b2f(hb[(brow + 1 + ny * 32 + nx) * 5460 + c]),
                             dw_w[(dy * 3 + dx) * HID_DIM + c], a);
                }
            }
            val = a;
        }
        float ge = 0.5f * val * (1.0f + erff(val * 0.70710678118654752f));
        act[row * KP_FC2 + c] = f2b(ge * b2f(hb[row * 5460 + HID_DIM + c]));
    }
}

// ---------------- launch ----------------
extern "C" void kernel_launch(void* const* d_in, const int* in_sizes, int n_in,
                              void* d_out, int out_size, void* d_ws, size_t ws_size,
                              hipStream_t stream) {
    const float* x      = (const float*)d_in[0];
    const float* g1     = (const float*)d_in[1];
    const float* w_qkv  = (const float*)d_in[2];
    const float* b_qkv  = (const float*)d_in[3];
    const float* w_proj = (const float*)d_in[4];
    const float* b_proj = (const float*)d_in[5];
    const float* g2     = (const float*)d_in[6];
    const float* fc1_w  = (const float*)d_in[7];
    const float* fc1_b  = (const float*)d_in[8];
    const float* dw_w   = (const float*)d_in[9];
    const float* dw_b   = (const float*)d_in[10];
    const float* fc2_w  = (const float*)d_in[11];
    const float* fc2_b  = (const float*)d_in[12];
    float* out = (float*)d_out;
    char* base = (char*)d_ws;

    // ---- phase 1 layout (47.7 MB) ----
    unsigned short* xnc   = (unsigned short*)(base + 0);          // 2176 x 1024
    unsigned short* qkv2  = (unsigned short*)(base + 4456448);    // 2176 x 3072
    unsigned short* Vt2   = (unsigned short*)(base + 17825792);   // 2x16x64x1088
    unsigned short* attnb = (unsigned short*)(base + 22282240);   // 8320 x 1024 (FULL)
    unsigned short* qkvT  = (unsigned short*)(base + 39321600);   // 3072 x 1024
    unsigned short* projT = (unsigned short*)(base + 45613056);   // 1024 x 1024  (end 47,710,208)
    // ---- phase 2 layout (52.9 MB) ----
    unsigned short* hbufb = (unsigned short*)(base + 4456448);    // 2050 x 5460  (end 26,842,448)
    unsigned short* actb  = (unsigned short*)(base + 26842624);   // 2050 x 2816  (end 38,388,224)
    unsigned short* fc1T  = (unsigned short*)(base + 38388224);   // 5504 x 1024  (end 49,660,416)
    unsigned short* fc2T  = (unsigned short*)(base + 49660416);   // 1024 x 2816  (end 55,427,584)

    // ---- attention phase ----
    convt_kernel<<<dim3(96, 32), 256, 0, stream>>>(w_qkv, qkvT, 1024, 3072, 1024);
    convt_kernel<<<dim3(32, 32), 256, 0, stream>>>(w_proj, projT, 1024, 1024, 1024);
    for (int c = 0; c < 4; c++) {
        size_t roff = (size_t)c * 2 * S_DIM;
        rmsnorm_kernel<<<2 * S_DIM, 256, 0, stream>>>(x + roff * E_DIM, g1, xnc);
        gemm_ring<true><<<dim3(24, 17), 256, 0, stream>>>(xnc, qkvT, b_qkv, nullptr,
                qkv2, 2 * S_DIM, 3072, 1024, 3072);
        rope_kernel<<<4100, 256, 0, stream>>>(qkv2);
        vtrans_kernel<<<dim3(17, 16, 2), 256, 0, stream>>>(qkv2, Vt2);
        attn_kernel<<<dim3(17, 16, 2), 256, 0, stream>>>(qkv2, Vt2,
                attnb + roff * E_DIM);
    }
    gemm_ring<false><<<dim3(8, 65), 256, 0, stream>>>(attnb, projT, b_proj,
            x, out, MROWS, 1024, 1024, 1024);

    // ---- MLP phase ----
    convt_kernel<<<dim3(171, 32), 256, 0, stream>>>(fc1_w, fc1T, 1024, 5460, 1024);
    convt_kernel<<<dim3(32, 86), 256, 0, stream>>>(fc2_w, fc2T, HID_DIM, 1024, KP_FC2);
    for (int c = 0; c < 4; c++) {
        size_t roff = (size_t)c * 2 * S_DIM;
        float* outc = out + roff * E_DIM;
        rmsnorm_kernel<<<2 * S_DIM, 256, 0, stream>>>(outc, g2, xnc);
        gemm_ring<true><<<dim3(43, 17), 256, 0, stream>>>(xnc, fc1T, fc1_b, nullptr,
                hbufb, 2 * S_DIM, 5460, 1024, 5460);
        conv_gelu_kernel<<<2 * S_DIM, 256, 0, stream>>>(hbufb, dw_w, dw_b, actb);
        gemm_ring<false><<<dim3(8, 17), 256, 0, stream>>>(actb, fc2T, fc2_b, outc,
                outc, 2 * S_DIM, 1024, KP_FC2, 1024);
    }
}

// Round 7
// 1085.396 us; speedup vs baseline: 2.2928x; 2.2928x over previous
//
#include <hip/hip_runtime.h>
#include <hip/hip_bf16.h>
#include <math.h>

#define E_DIM 1024
#define NHEAD 16
#define HID_DIM 2730
#define KP_FC2 2752            // fc2 K padded (zero weight rows) -> mult of 32
#define HB_LD 5504             // hbuf row stride (16B-aligned)
#define B_DIM 8
#define S_DIM 1025
#define EPS_V 1e-6f
#define SCALE_V 0.125f
#define MROWS (B_DIM * S_DIM)   // 8200

typedef __attribute__((ext_vector_type(8))) short short8;
typedef __attribute__((ext_vector_type(4))) float f32x4;
typedef unsigned short us;

__device__ __forceinline__ float b2f(us u) {
    union { unsigned int i; float f; } x; x.i = ((unsigned int)u) << 16; return x.f;
}
__device__ __forceinline__ us f2b(float f) {
    __hip_bfloat16 h = __float2bfloat16(f);
    return *reinterpret_cast<us*>(&h);
}

__device__ __forceinline__ void stage16(const void* g, void* l) {
    __builtin_amdgcn_global_load_lds(
        (const __attribute__((address_space(1))) unsigned int*)g,
        (__attribute__((address_space(3))) unsigned int*)l,
        16, 0, 0);
}

// u16 index of the 8-element group at (row, c8) in a XOR-swizzled [64][64] bf16 tile
__device__ __forceinline__ int sl(int row, int c8) {
    return (row * 8 + (c8 ^ (row & 7))) * 8;
}

// ---------------- RMSNorm (fp32 in -> bf16 out) ----------------
__global__ __launch_bounds__(256) void rmsnorm_kernel(const float* __restrict__ x,
        const float* __restrict__ g, us* __restrict__ out) {
    int row = blockIdx.x;
    const float4* xr = (const float4*)(x + (size_t)row * E_DIM);
    float4 v = xr[threadIdx.x];
    float ss = v.x*v.x + v.y*v.y + v.z*v.z + v.w*v.w;
    #pragma unroll
    for (int off = 32; off > 0; off >>= 1) ss += __shfl_down(ss, off, 64);
    __shared__ float wsum[4];
    int lane = threadIdx.x & 63, w = threadIdx.x >> 6;
    if (lane == 0) wsum[w] = ss;
    __syncthreads();
    float tot = wsum[0] + wsum[1] + wsum[2] + wsum[3];
    float inv = rsqrtf(tot * (1.0f / E_DIM) + EPS_V);
    float4 gv = ((const float4*)g)[threadIdx.x];
    ushort4 o;
    o.x = f2b(v.x * inv * gv.x); o.y = f2b(v.y * inv * gv.y);
    o.z = f2b(v.z * inv * gv.z); o.w = f2b(v.w * inv * gv.w);
    ((ushort4*)(out + (size_t)row * E_DIM))[threadIdx.x] = o;
}

// ---------------- weight convert+transpose: W[K][N] f32 -> WT[n][k] bf16 ----------------
// swap_half: output row n sources original column (n<swap ? n+swap : n-swap) for n<N.
__global__ __launch_bounds__(256) void convt_kernel(const float* __restrict__ W,
        us* __restrict__ WT, int K, int N, int KPad, int swap_half) {
    __shared__ float T[32][33];
    int n0 = blockIdx.x * 32, k0 = blockIdx.y * 32;
    int c = threadIdx.x & 31, r4 = (threadIdx.x >> 5) << 2;
    #pragma unroll
    for (int i = 0; i < 4; i++) {
        int k = k0 + r4 + i, n = n0 + c;
        int src = n;
        if (swap_half && n < N) src = (n < swap_half) ? n + swap_half : n - swap_half;
        T[c][r4 + i] = (k < K && n < N) ? W[(size_t)k * N + src] : 0.0f;
    }
    __syncthreads();
    #pragma unroll
    for (int i = 0; i < 4; i++) {
        int n = n0 + r4 + i, k = k0 + c;
        if (n < N && k < KPad) WT[(size_t)n * KPad + k] = f2b(T[r4 + i][c]);
    }
}

// ---------------- fc1 bias permute: bp[r] = b[r<H ? r+H : r-H] ----------------
__global__ __launch_bounds__(256) void bias_perm_kernel(const float* __restrict__ b,
        float* __restrict__ bp) {
    int r = blockIdx.x * 256 + threadIdx.x;
    if (r < 2 * HID_DIM) bp[r] = b[r < HID_DIM ? r + HID_DIM : r - HID_DIM];
}

// ---------------- bf16 MFMA GEMM, double-buffered LDS staging (round-5 proven) ----------------
// A: [M][lda] bf16, Bt: [N][K] bf16, K % 32 == 0; buffers padded to 128-row tiles.
template<bool BF16OUT>
__global__ __launch_bounds__(256) void gemm_mfma(const us* __restrict__ A, int lda,
        const us* __restrict__ Bt, const float* __restrict__ bias,
        const float* __restrict__ Rres, void* __restrict__ Cv,
        int M, int N, int K, int ldc) {
    __shared__ __align__(16) us ldsA[2][4096];
    __shared__ __align__(16) us ldsB[2][4096];
    int tid = threadIdx.x;
    int lane = tid & 63;
    int w = tid >> 6;
    int wm = w >> 1, wn = w & 1;
    int m0 = blockIdx.y * 128, n0 = blockIdx.x * 128;

    int c0 = 2 * w, c1 = 2 * w + 1;
    int kc0 = c0 & 3, rh0 = (c0 >> 2) * 64;
    int kc1 = c1 & 3, rh1 = (c1 >> 2) * 64;
    const us* gA0 = A + (size_t)(m0 + rh0 + lane) * lda + kc0 * 8;
    const us* gA1 = A + (size_t)(m0 + rh1 + lane) * lda + kc1 * 8;
    const us* gB0 = Bt + (size_t)(n0 + rh0 + lane) * K + kc0 * 8;
    const us* gB1 = Bt + (size_t)(n0 + rh1 + lane) * K + kc1 * 8;
    unsigned int off0 = (kc0 * 128 + rh0) * 8;
    unsigned int off1 = (kc1 * 128 + rh1) * 8;
    unsigned int offPa = ((lane >> 4) * 128 + wm * 64 + (lane & 15)) * 8;
    unsigned int offPb = ((lane >> 4) * 128 + wn * 64 + (lane & 15)) * 8;

    f32x4 acc[4][4];
    #pragma unroll
    for (int i = 0; i < 4; i++)
        #pragma unroll
        for (int j = 0; j < 4; j++) acc[i][j] = (f32x4){0.f, 0.f, 0.f, 0.f};

    int nk = K >> 5;
    stage16(gA0, &ldsA[0][off0]);
    stage16(gA1, &ldsA[0][off1]);
    stage16(gB0, &ldsB[0][off0]);
    stage16(gB1, &ldsB[0][off1]);

    for (int t = 0; t < nk; t++) {
        int cur = t & 1, nxt = cur ^ 1;
        __syncthreads();
        if (t + 1 < nk) {
            int k0 = (t + 1) << 5;
            stage16(gA0 + k0, &ldsA[nxt][off0]);
            stage16(gA1 + k0, &ldsA[nxt][off1]);
            stage16(gB0 + k0, &ldsB[nxt][off0]);
            stage16(gB1 + k0, &ldsB[nxt][off1]);
        }
        const us* pa = &ldsA[cur][offPa];
        const us* pb = &ldsB[cur][offPb];
        short8 af[4], bfr[4];
        #pragma unroll
        for (int i = 0; i < 4; i++) af[i] = *(const short8*)(pa + i * 128);
        #pragma unroll
        for (int j = 0; j < 4; j++) bfr[j] = *(const short8*)(pb + j * 128);
        #pragma unroll
        for (int i = 0; i < 4; i++)
            #pragma unroll
            for (int j = 0; j < 4; j++)
                acc[i][j] = __builtin_amdgcn_mfma_f32_16x16x32_bf16(af[i], bfr[j], acc[i][j], 0, 0, 0);
    }

    int cr = (lane >> 4) * 4;
    int cc = lane & 15;
    #pragma unroll
    for (int i = 0; i < 4; i++) {
        int gmb = m0 + wm * 64 + i * 16 + cr;
        #pragma unroll
        for (int j = 0; j < 4; j++) {
            int gn = n0 + wn * 64 + j * 16 + cc;
            if (gn >= N) continue;
            float bs = bias[gn];
            #pragma unroll
            for (int r = 0; r < 4; r++) {
                int gm = gmb + r;
                if (gm >= M) continue;
                float v = acc[i][j][r] + bs;
                if (BF16OUT) {
                    ((us*)Cv)[(size_t)gm * ldc + gn] = f2b(v);
                } else {
                    ((float*)Cv)[(size_t)gm * ldc + gn] = v + Rres[(size_t)gm * ldc + gn];
                }
            }
        }
    }
}

// ---------------- RoPE (in-place over R rows) + q*SCALE ----------------
__global__ __launch_bounds__(256) void rope_kernel(us* __restrict__ qkv) {
    int idx = blockIdx.x * 256 + threadIdx.x;
    int i = idx & 31;
    int h = (idx >> 5) & (NHEAD - 1);
    int rc = idx >> 9;
    int s = rc % S_DIM;
    us* q = qkv + (size_t)rc * 3072 + h * 64;
    us* k = q + 1024;
    if (s == 0) {
        q[i] = f2b(b2f(q[i]) * SCALE_V);
        q[i + 32] = f2b(b2f(q[i + 32]) * SCALE_V);
        return;
    }
    float pos = (float)(s - 1);
    float invf = expf((float)i * (-9.210340371976184f / 32.0f));
    float f = pos * invf;
    float c = cosf(f), sn = sinf(f);
    float q1 = b2f(q[i]), q2 = b2f(q[i + 32]);
    q[i]      = f2b((q1 * c - q2 * sn) * SCALE_V);
    q[i + 32] = f2b((q2 * c + q1 * sn) * SCALE_V);
    float k1 = b2f(k[i]), k2 = b2f(k[i + 32]);
    k[i]      = f2b(k1 * c - k2 * sn);
    k[i + 32] = f2b(k2 * c + k1 * sn);
}

// ---------------- V transpose: qkv v-section -> Vt[bc][h][d][1088] ----------------
__global__ __launch_bounds__(256) void vtrans_kernel(const us* __restrict__ qkv,
        us* __restrict__ Vt) {
    __shared__ us T[64][65];
    int st = blockIdx.x, h = blockIdx.y, bc = blockIdx.z;
    int tid = threadIdx.x;
    int r = tid & 63, cb = (tid >> 6) * 16;
    const us* src = qkv + (size_t)(bc * S_DIM + st * 64 + r) * 3072 + 2048 + h * 64 + cb;
    #pragma unroll
    for (int i = 0; i < 4; i++) {
        ushort4 v = *(const ushort4*)(src + i * 4);
        T[cb + i*4 + 0][r] = v.x; T[cb + i*4 + 1][r] = v.y;
        T[cb + i*4 + 2][r] = v.z; T[cb + i*4 + 3][r] = v.w;
    }
    __syncthreads();
    int d = tid >> 2, sc = (tid & 3) * 16;
    us* dst = Vt + ((size_t)((bc * 16 + h) * 64 + d)) * 1088 + st * 64 + sc;
    #pragma unroll
    for (int g = 0; g < 4; g++) {
        ushort4 o;
        int i0 = sc + g * 4;
        o.x = (st*64 + i0 + 0 < S_DIM) ? T[d][i0 + 0] : 0;
        o.y = (st*64 + i0 + 1 < S_DIM) ? T[d][i0 + 1] : 0;
        o.z = (st*64 + i0 + 2 < S_DIM) ? T[d][i0 + 2] : 0;
        o.w = (st*64 + i0 + 3 < S_DIM) ? T[d][i0 + 3] : 0;
        *(ushort4*)(dst + g * 4) = o;
    }
}

// ---------------- MFMA flash attention (proven round-4 structure) ----------------
__global__ __launch_bounds__(256) void attn_kernel(const us* __restrict__ qkv,
        const us* __restrict__ Vt, us* __restrict__ attnb) {
    __shared__ __align__(16) us Qs[4096];
    __shared__ __align__(16) us Ks[4096];
    __shared__ __align__(16) us Vts[4096];
    __shared__ __align__(16) us Ps[4096];
    int qt = blockIdx.x, h = blockIdx.y, bc = blockIdx.z;
    int tid = threadIdx.x;
    int lane = tid & 63, w = tid >> 6;
    int l15 = lane & 15, quad = lane >> 4;

    const us* qg = qkv + (size_t)(bc * S_DIM + qt * 64) * 3072 + h * 64;
    #pragma unroll
    for (int i = 0; i < 2; i++) {
        int slot = i * 256 + tid;
        int row = slot >> 3, c8 = (slot & 7) ^ (row & 7);
        stage16(qg + (size_t)row * 3072 + c8 * 8, Qs + slot * 8);
    }
    const us* kg = qkv + (size_t)(bc * S_DIM) * 3072 + 1024 + h * 64;
    const us* vgp = Vt + (size_t)((bc * 16 + h) * 64) * 1088;

    f32x4 acc_o[4];
    float mr[4], lr[4];
    #pragma unroll
    for (int r = 0; r < 4; r++) { mr[r] = -1e30f; lr[r] = 0.f; }
    #pragma unroll
    for (int j = 0; j < 4; j++) acc_o[j] = (f32x4){0.f, 0.f, 0.f, 0.f};

    for (int kt = 0; kt < 17; kt++) {
        __syncthreads();
        #pragma unroll
        for (int i = 0; i < 2; i++) {
            int slot = i * 256 + tid;
            int row = slot >> 3, c8 = (slot & 7) ^ (row & 7);
            stage16(kg + (size_t)(kt * 64 + row) * 3072 + c8 * 8, Ks + slot * 8);
            stage16(vgp + (size_t)row * 1088 + kt * 64 + c8 * 8, Vts + slot * 8);
        }
        __syncthreads();

        f32x4 accS[4];
        #pragma unroll
        for (int j = 0; j < 4; j++) accS[j] = (f32x4){0.f, 0.f, 0.f, 0.f};
        short8 qa0 = *(const short8*)(Qs + sl(16 * w + l15, quad));
        short8 qa1 = *(const short8*)(Qs + sl(16 * w + l15, 4 + quad));
        #pragma unroll
        for (int j = 0; j < 4; j++) {
            short8 kb0 = *(const short8*)(Ks + sl(16 * j + l15, quad));
            short8 kb1 = *(const short8*)(Ks + sl(16 * j + l15, 4 + quad));
            accS[j] = __builtin_amdgcn_mfma_f32_16x16x32_bf16(qa0, kb0, accS[j], 0, 0, 0);
            accS[j] = __builtin_amdgcn_mfma_f32_16x16x32_bf16(qa1, kb1, accS[j], 0, 0, 0);
        }
        float pr[4][4];
        #pragma unroll
        for (int j = 0; j < 4; j++) {
            if (kt * 64 + 16 * j + l15 >= S_DIM) {
                #pragma unroll
                for (int r = 0; r < 4; r++) accS[j][r] = -1e30f;
            }
        }
        #pragma unroll
        for (int r = 0; r < 4; r++) {
            float tm = fmaxf(fmaxf(accS[0][r], accS[1][r]), fmaxf(accS[2][r], accS[3][r]));
            #pragma unroll
            for (int off = 1; off < 16; off <<= 1)
                tm = fmaxf(tm, __shfl_xor(tm, off, 64));
            float mnew = fmaxf(mr[r], tm);
            float al = __expf(mr[r] - mnew);
            mr[r] = mnew;
            float rs = 0.f;
            #pragma unroll
            for (int j = 0; j < 4; j++) {
                float p = __expf(accS[j][r] - mnew);
                pr[j][r] = p;
                rs += p;
            }
            #pragma unroll
            for (int off = 1; off < 16; off <<= 1)
                rs += __shfl_xor(rs, off, 64);
            lr[r] = lr[r] * al + rs;
            #pragma unroll
            for (int j = 0; j < 4; j++) acc_o[j][r] *= al;
        }
        #pragma unroll
        for (int j = 0; j < 4; j++) {
            #pragma unroll
            for (int r = 0; r < 4; r++) {
                int prow = quad * 4 + r;
                int idx = sl(16 * w + prow, 2 * j + (l15 >> 3)) + (l15 & 7);
                Ps[idx] = f2b(pr[j][r]);
            }
        }
        short8 pa0 = *(const short8*)(Ps + sl(16 * w + l15, quad));
        short8 pa1 = *(const short8*)(Ps + sl(16 * w + l15, 4 + quad));
        #pragma unroll
        for (int j = 0; j < 4; j++) {
            short8 vb0 = *(const short8*)(Vts + sl(16 * j + l15, quad));
            short8 vb1 = *(const short8*)(Vts + sl(16 * j + l15, 4 + quad));
            acc_o[j] = __builtin_amdgcn_mfma_f32_16x16x32_bf16(pa0, vb0, acc_o[j], 0, 0, 0);
            acc_o[j] = __builtin_amdgcn_mfma_f32_16x16x32_bf16(pa1, vb1, acc_o[j], 0, 0, 0);
        }
    }
    #pragma unroll
    for (int r = 0; r < 4; r++) {
        int s = qt * 64 + 16 * w + quad * 4 + r;
        if (s >= S_DIM) continue;
        float invl = 1.0f / lr[r];
        #pragma unroll
        for (int j = 0; j < 4; j++)
            attnb[(size_t)(bc * S_DIM + s) * E_DIM + h * 64 + 16 * j + l15] =
                f2b(acc_o[j][r] * invl);
    }
}

// ---------------- depthwise conv + GELU + gate, IN-PLACE on [vg|xg] hbuf ----------------
// hbuf row: cols [0,2730) = vg (channel c at col c), cols [2730,5460) = xg (channel c
// at col 2730+c). Writes gated result into col c. Stride HB_LD.
__global__ __launch_bounds__(256) void conv_gelu_kernel(us* __restrict__ hb,
        const float* __restrict__ dw_w, const float* __restrict__ dw_b) {
    int p = blockIdx.x % S_DIM;
    size_t row = blockIdx.x;
    size_t brow = row - p;
    for (int c = threadIdx.x; c < HID_DIM; c += 256) {
        float val;
        if (p == 0) {
            val = b2f(hb[row * HB_LD + HID_DIM + c]);
        } else {
            int pp = p - 1;
            int gy = pp >> 5, gx = pp & 31;
            float a = dw_b[c];
            #pragma unroll
            for (int dy = 0; dy < 3; dy++) {
                int ny = gy + dy - 1;
                if (ny < 0 || ny >= 32) continue;
                #pragma unroll
                for (int dx = 0; dx < 3; dx++) {
                    int nx = gx + dx - 1;
                    if (nx < 0 || nx >= 32) continue;
                    a = fmaf(b2f(hb[(brow + 1 + ny * 32 + nx) * HB_LD + HID_DIM + c]),
                             dw_w[(dy * 3 + dx) * HID_DIM + c], a);
                }
            }
            val = a;
        }
        float ge = 0.5f * val * (1.0f + erff(val * 0.70710678118654752f));
        hb[row * HB_LD + c] = f2b(ge * b2f(hb[row * HB_LD + c]));
    }
}

// ---------------- launch ----------------
static size_t ws_need(int cb) {
    size_t R = (size_t)cb * 1025, Rp = ((R + 127) / 128) * 128;
    size_t end1 = Rp*1024*2 + Rp*3072*2 + (size_t)cb*16*64*1088*2
                + 8320ull*1024*2 + 3072ull*1024*2 + 1024ull*1024*2;
    size_t end2 = Rp*1024*2 + Rp*HB_LD*2 + 5504ull*1024*2 + 1024ull*KP_FC2*2 + 5460*4;
    return end1 > end2 ? end1 : end2;
}

extern "C" void kernel_launch(void* const* d_in, const int* in_sizes, int n_in,
                              void* d_out, int out_size, void* d_ws, size_t ws_size,
                              hipStream_t stream) {
    const float* x      = (const float*)d_in[0];
    const float* g1     = (const float*)d_in[1];
    const float* w_qkv  = (const float*)d_in[2];
    const float* b_qkv  = (const float*)d_in[3];
    const float* w_proj = (const float*)d_in[4];
    const float* b_proj = (const float*)d_in[5];
    const float* g2     = (const float*)d_in[6];
    const float* fc1_w  = (const float*)d_in[7];
    const float* fc1_b  = (const float*)d_in[8];
    const float* dw_w   = (const float*)d_in[9];
    const float* dw_b   = (const float*)d_in[10];
    const float* fc2_w  = (const float*)d_in[11];
    const float* fc2_b  = (const float*)d_in[12];
    float* out = (float*)d_out;
    char* base = (char*)d_ws;

    // chunk size adapted to ws_size (constant per session -> same work every call)
    int CB = 2;
    if (ws_size >= ws_need(8)) CB = 8;
    else if (ws_size >= ws_need(4)) CB = 4;
    int NC = B_DIM / CB;
    size_t R = (size_t)CB * 1025, Rp = ((R + 127) / 128) * 128;
    int gy = (int)((R + 127) / 128);

    // phase-1 layout
    us* xn    = (us*)base;                       // Rp x 1024
    size_t o  = Rp * 1024 * 2;
    us* qkv   = (us*)(base + o);                 // Rp x 3072 (phase1)
    us* hbuf  = (us*)(base + o);                 // Rp x HB_LD (phase2 overlay)
    size_t o2 = o + Rp * 3072 * 2;
    us* Vt    = (us*)(base + o2);                // CB x 16 x 64 x 1088
    size_t o3 = o2 + (size_t)CB * 16 * 64 * 1088 * 2;
    us* attnb = (us*)(base + o3);                // 8320 x 1024
    size_t o4 = o3 + 8320ull * 1024 * 2;
    us* qkvT  = (us*)(base + o4);                // 3072 x 1024
    size_t o5 = o4 + 3072ull * 1024 * 2;
    us* projT = (us*)(base + o5);                // 1024 x 1024
    // phase-2 layout (overlays qkv/Vt/attnb/qkvT/projT)
    size_t p2 = o + Rp * HB_LD * 2;
    us* fc1T  = (us*)(base + p2);                // 5504 x 1024 (rows >=5460 garbage, masked)
    size_t p3 = p2 + 5504ull * 1024 * 2;
    us* fc2T  = (us*)(base + p3);                // 1024 x KP_FC2
    float* fc1bp = (float*)(base + p3 + 1024ull * KP_FC2 * 2);   // 5460 f32

    // ---- attention phase ----
    convt_kernel<<<dim3(96, 32), 256, 0, stream>>>(w_qkv, qkvT, 1024, 3072, 1024, 0);
    convt_kernel<<<dim3(32, 32), 256, 0, stream>>>(w_proj, projT, 1024, 1024, 1024, 0);
    for (int c = 0; c < NC; c++) {
        size_t roff = (size_t)c * R;
        rmsnorm_kernel<<<(int)R, 256, 0, stream>>>(x + roff * E_DIM, g1, xn);
        gemm_mfma<true><<<dim3(24, gy), 256, 0, stream>>>(xn, 1024, qkvT, b_qkv, nullptr,
                qkv, (int)R, 3072, 1024, 3072);
        rope_kernel<<<(int)(2 * R), 256, 0, stream>>>(qkv);
        vtrans_kernel<<<dim3(17, 16, CB), 256, 0, stream>>>(qkv, Vt);
        attn_kernel<<<dim3(17, 16, CB), 256, 0, stream>>>(qkv, Vt, attnb + roff * E_DIM);
    }
    gemm_mfma<false><<<dim3(8, 65), 256, 0, stream>>>(attnb, 1024, projT, b_proj,
            x, out, MROWS, 1024, 1024, 1024);

    // ---- MLP phase ----
    convt_kernel<<<dim3(171, 32), 256, 0, stream>>>(fc1_w, fc1T, 1024, 5460, 1024, HID_DIM);
    convt_kernel<<<dim3(32, 86), 256, 0, stream>>>(fc2_w, fc2T, HID_DIM, 1024, KP_FC2, 0);
    bias_perm_kernel<<<22, 256, 0, stream>>>(fc1_b, fc1bp);
    for (int c = 0; c < NC; c++) {
        size_t roff = (size_t)c * R;
        float* outc = out + roff * E_DIM;
        rmsnorm_kernel<<<(int)R, 256, 0, stream>>>(outc, g2, xn);
        gemm_mfma<true><<<dim3(43, gy), 256, 0, stream>>>(xn, 1024, fc1T, fc1bp, nullptr,
                hbuf, (int)R, 5460, 1024, HB_LD);
        conv_gelu_kernel<<<(int)R, 256, 0, stream>>>(hbuf, dw_w, dw_b);
        gemm_mfma<false><<<dim3(8, gy), 256, 0, stream>>>(hbuf, HB_LD, fc2T, fc2_b, outc,
                outc, (int)R, 1024, KP_FC2, 1024);
    }
}